// Round 2
// baseline (4964.723 us; speedup 1.0000x reference)
//
#include <hip/hip_runtime.h>
#include <cmath>

using bf16 = __bf16;
typedef short short8 __attribute__((ext_vector_type(8)));
typedef short short4v __attribute__((ext_vector_type(4)));
typedef float f32x4 __attribute__((ext_vector_type(4)));
typedef __bf16 bf16x4 __attribute__((ext_vector_type(4)));

#define TD 6272   // B*S tokens
#define DM 768
#define FF 3072
#define NL 12
#define NH 12
#define SQ 784
#define NB 8

// ---- 16x16x16 bf16 MFMA (K=16): builtin if available, else raw asm ----
#if defined(__has_builtin)
#if __has_builtin(__builtin_amdgcn_mfma_f32_16x16x16bf16_1k)
#define HAVE_MFMA16BUILTIN 1
#endif
#if __has_builtin(__builtin_amdgcn_exp2f)
#define HAVE_EXP2BUILTIN 1
#endif
#endif
static __device__ inline f32x4 mfma16x16x16_bf16(short4v a, short4v b, f32x4 c) {
#ifdef HAVE_MFMA16BUILTIN
  return __builtin_amdgcn_mfma_f32_16x16x16bf16_1k(a, b, c, 0, 0, 0);
#else
  asm volatile("v_mfma_f32_16x16x16_bf16 %0, %1, %2, %0" : "+v"(c) : "v"(a), "v"(b));
  return c;
#endif
}
static __device__ inline float exp2fast(float x) {
#ifdef HAVE_EXP2BUILTIN
  return __builtin_amdgcn_exp2f(x);
#else
  return exp2f(x);
#endif
}

// ---------- LayerNorm: fp32 in -> OutT out (one wave per token) ----------
template <typename OutT>
__global__ __launch_bounds__(64) void ln_kernel(const float* __restrict__ in,
    const float* __restrict__ s, const float* __restrict__ b, OutT* __restrict__ out) {
  const int t = blockIdx.x;
  const int lane = threadIdx.x;
  const float* row = in + (size_t)t * DM;
  float x[12];
  float sum = 0.f, sq = 0.f;
#pragma unroll
  for (int j = 0; j < 12; ++j) {
    x[j] = row[lane + 64 * j];
    sum += x[j];
    sq += x[j] * x[j];
  }
#pragma unroll
  for (int off = 32; off >= 1; off >>= 1) {
    sum += __shfl_xor(sum, off);
    sq  += __shfl_xor(sq, off);
  }
  const float mean = sum * (1.f / DM);
  const float var  = sq * (1.f / DM) - mean * mean;
  const float rstd = rsqrtf(var + 1e-6f);
  OutT* orow = out + (size_t)t * DM;
#pragma unroll
  for (int j = 0; j < 12; ++j) {
    int c = lane + 64 * j;
    orow[c] = (OutT)((x[j] - mean) * rstd * s[c] + b[c]);
  }
}

// ---------- transpose + downcast: in fp32 (R x C) -> out bf16 (C x R) ----------
__global__ void transpose_kernel(const float* __restrict__ in, bf16* __restrict__ out,
                                 int R, int C) {
  __shared__ bf16 tile[32][33];
  const int bx = blockIdx.x * 32;  // col base (in)
  const int by = blockIdx.y * 32;  // row base (in)
  const int tx = threadIdx.x, ty = threadIdx.y;  // (32, 8)
#pragma unroll
  for (int j = 0; j < 32; j += 8)
    tile[ty + j][tx] = (bf16)in[(size_t)(by + ty + j) * C + bx + tx];
  __syncthreads();
#pragma unroll
  for (int j = 0; j < 32; j += 8)
    out[(size_t)(bx + ty + j) * R + by + tx] = tile[tx][ty + j];
}

// ---------- V head-transpose: vbuf [B,S,D] -> vt [B*H][64][784] (bf16) ----------
__global__ void vt_kernel(const bf16* __restrict__ vbuf, bf16* __restrict__ vt) {
  __shared__ bf16 tile[32][33];
  const int bh = blockIdx.z;
  const int b = bh / NH, h = bh % NH;
  const int s0 = blockIdx.x * 32, d0 = blockIdx.y * 32;
  const int tx = threadIdx.x, ty = threadIdx.y;  // (32,8)
  const bf16* src = vbuf + ((size_t)b * SQ) * DM + h * 64;
#pragma unroll
  for (int j = 0; j < 32; j += 8) {
    int s = s0 + ty + j;
    if (s < SQ) tile[ty + j][tx] = src[(size_t)s * DM + d0 + tx];
  }
  __syncthreads();
  bf16* dst = vt + (size_t)bh * 64 * SQ;
  if (s0 + tx < SQ) {
#pragma unroll
    for (int j = 0; j < 32; j += 8)
      dst[(size_t)(d0 + ty + j) * SQ + s0 + tx] = tile[tx][ty + j];
  }
}

// ---------- GEMM: C = A(MxK) * W(KxN) + bias, W given transposed Bt (NxK), bf16 MFMA ----------
// EPI 0: bias -> bf16 out ; EPI 1: bias + exact GELU -> bf16 ; EPI 2: bias + residual(fp32) -> fp32
template <int EPI>
__global__ __launch_bounds__(256) void gemm_kernel(
    const bf16* __restrict__ A, const bf16* __restrict__ Bt,
    const float* __restrict__ bias, const float* __restrict__ res,
    bf16* __restrict__ outb, float* __restrict__ outf,
    int M, int N, int K) {
  __shared__ bf16 As[128 * 32];
  __shared__ bf16 Bs[128 * 32];
  const int tid = threadIdx.x;
  const int lane = tid & 63;
  const int wid = tid >> 6;
  const size_t m0 = (size_t)blockIdx.x * 128;
  const size_t n0 = (size_t)blockIdx.y * 128;
  const int wm = (wid >> 1) * 64;
  const int wn = (wid & 1) * 64;
  const int lr = lane & 15;
  const int lq = lane >> 4;

  f32x4 acc[4][4] = {};

  const int vi0 = wid * 64 + lane;
  const int vi1 = vi0 + 256;
  const bf16* ga0 = A + (m0 + (vi0 >> 2)) * (size_t)K + (vi0 & 3) * 8;
  const bf16* ga1 = A + (m0 + (vi1 >> 2)) * (size_t)K + (vi1 & 3) * 8;
  const bf16* gb0 = Bt + (n0 + (vi0 >> 2)) * (size_t)K + (vi0 & 3) * 8;
  const bf16* gb1 = Bt + (n0 + (vi1 >> 2)) * (size_t)K + (vi1 & 3) * 8;
  bf16* la0 = As + (size_t)(wid * 64) * 8;
  bf16* la1 = As + (size_t)(wid * 64 + 256) * 8;
  bf16* lb0 = Bs + (size_t)(wid * 64) * 8;
  bf16* lb1 = Bs + (size_t)(wid * 64 + 256) * 8;

  for (int kb = 0; kb < K; kb += 32) {
    __builtin_amdgcn_global_load_lds(ga0, la0, 16, 0, 0);
    __builtin_amdgcn_global_load_lds(ga1, la1, 16, 0, 0);
    __builtin_amdgcn_global_load_lds(gb0, lb0, 16, 0, 0);
    __builtin_amdgcn_global_load_lds(gb1, lb1, 16, 0, 0);
    ga0 += 32; ga1 += 32; gb0 += 32; gb1 += 32;
    __syncthreads();
    short8 af[4], bfr[4];
#pragma unroll
    for (int t = 0; t < 4; ++t) {
      af[t]  = *(const short8*)(As + (wm + t * 16 + lr) * 32 + lq * 8);
      bfr[t] = *(const short8*)(Bs + (wn + t * 16 + lr) * 32 + lq * 8);
    }
#pragma unroll
    for (int ti = 0; ti < 4; ++ti)
#pragma unroll
      for (int tj = 0; tj < 4; ++tj)
        acc[ti][tj] = __builtin_amdgcn_mfma_f32_16x16x32_bf16(af[ti], bfr[tj], acc[ti][tj], 0, 0, 0);
    __syncthreads();
  }

#pragma unroll
  for (int ti = 0; ti < 4; ++ti) {
    const size_t row_base = m0 + wm + ti * 16 + lq * 4;
#pragma unroll
    for (int tj = 0; tj < 4; ++tj) {
      const size_t col = n0 + wn + tj * 16 + lr;
      const float bsv = bias[col];
#pragma unroll
      for (int r = 0; r < 4; ++r) {
        const size_t idx = (row_base + r) * (size_t)N + col;
        float vacc = acc[ti][tj][r] + bsv;
        if constexpr (EPI == 1) vacc = 0.5f * vacc * (1.0f + erff(vacc * 0.70710678118654752f));
        if constexpr (EPI == 2) {
          outf[idx] = res[idx] + vacc;
        } else {
          outb[idx] = (bf16)vacc;
        }
      }
    }
  }
}

// ---------- MFMA flash attention, KVBLK=64 ----------
// One wave per 16-query tile, independent (no LDS, no barriers). Per 64-k step:
// 4 QK^T subtiles (8 MFMA) -> ONE max/softmax pass (raw-score max, p = exp2(fma(s,c2,-mb))),
// deferred acc rescale (skip unless a lane's max grew past THR), 16 PV MFMA.
// S^T = K·Q^T via 16x16x32; C/D layout of S^T equals B-operand layout of 16x16x16,
// so P^T feeds ctx^T = V^T·P^T with no cross-lane moves. vt: [B*H][64][784].
// 784 = 12*64 + 16: tail step is a single fully-valid 16-subtile (no masking needed).
__global__ __launch_bounds__(256, 4) void attn_kernel(const bf16* __restrict__ q,
    const bf16* __restrict__ k, const bf16* __restrict__ vt, bf16* __restrict__ ctx) {
  const int tid = threadIdx.x;
  const int wid = tid >> 6, lane = tid & 63;
  const int lr = lane & 15, lq = lane >> 4;
  const int bh = blockIdx.y;
  const int b = bh / NH, h = bh % NH;
  const int qt = blockIdx.x * 4 + wid;  // query tile 0..48 (49 tiles of 16)
  if (qt >= 49) return;
  const int q0 = qt * 16;

  const size_t qkbase = ((size_t)b * SQ) * DM + h * 64;
  const bf16* qrow = q + qkbase + (size_t)(q0 + lr) * DM + lq * 8;
  short8 qf0 = *(const short8*)(qrow);        // B-frag: Q[q0+lr][8lq..+7]
  short8 qf1 = *(const short8*)(qrow + 32);   //          d+32

  const bf16* kbase = k + qkbase + (size_t)lr * DM + lq * 8;
  const bf16* vtb = vt + (size_t)bh * 64 * SQ + (size_t)lr * SQ + 4 * lq;

  f32x4 acc[4] = {};            // ctx^T m-tiles (d 0-15,16-31,32-47,48-63)
  float mb = -1e30f;            // running max in (score*log2e*scale) domain, col q = lr
  float ls = 0.f;               // running sum (same p-scaling convention)
  const float c2 = 0.125f * 1.44269504088896f;  // 1/sqrt(64) * log2(e)

  // QK^T 16-k subtile: returns raw S^T[k0s+4lq+r][q0+lr] in s4[r]
  auto qk_subtile = [&](int k0s) -> f32x4 {
    const bf16* kr = kbase + (size_t)k0s * DM;
    short8 kf0 = *(const short8*)(kr);        // A-frag: K[k0s+lr][8lq..+7]
    short8 kf1 = *(const short8*)(kr + 32);
    f32x4 s4 = {};
    s4 = __builtin_amdgcn_mfma_f32_16x16x32_bf16(kf0, qf0, s4, 0, 0, 0);
    s4 = __builtin_amdgcn_mfma_f32_16x16x32_bf16(kf1, qf1, s4, 0, 0, 0);
    return s4;
  };
  // softmax-exp + PV for one 16-k subtile; returns per-lane partial sum of p
  auto soft_pv = [&](const f32x4 s4, int k0s) -> float {
    float p0 = exp2fast(fmaf(s4[0], c2, -mb));
    float p1 = exp2fast(fmaf(s4[1], c2, -mb));
    float p2 = exp2fast(fmaf(s4[2], c2, -mb));
    float p3 = exp2fast(fmaf(s4[3], c2, -mb));
    bf16x4 pb;
    pb[0] = (bf16)p0; pb[1] = (bf16)p1; pb[2] = (bf16)p2; pb[3] = (bf16)p3;
    const short4v pbv = __builtin_bit_cast(short4v, pb);
    const bf16* vp = vtb + k0s;
#pragma unroll
    for (int mt = 0; mt < 4; ++mt) {
      short4v vf = *(const short4v*)(vp + (size_t)mt * 16 * SQ);
      acc[mt] = mfma16x16x16_bf16(vf, pbv, acc[mt]);
    }
    return (p0 + p1) + (p2 + p3);
  };
  // deferred-max update/rescale for this step's raw column-max tm
  auto rescale = [&](float tm) {
    const float tmc = tm * c2;
    if (!__all(tmc <= mb + 11.5f)) {   // THR = 8 nats; p bounded by e^8
      const float mbn = fmaxf(mb, tmc);
      const float al = exp2fast(mb - mbn);
#pragma unroll
      for (int mt = 0; mt < 4; ++mt)
#pragma unroll
        for (int r = 0; r < 4; ++r) acc[mt][r] *= al;
      ls *= al;
      mb = mbn;
    }
  };

  for (int kt = 0; kt < 12; ++kt) {
    const int k0 = kt * 64;
    f32x4 s0 = qk_subtile(k0);
    f32x4 s1 = qk_subtile(k0 + 16);
    f32x4 s2 = qk_subtile(k0 + 32);
    f32x4 s3 = qk_subtile(k0 + 48);
    float tm = fmaxf(fmaxf(fmaxf(s0[0], s0[1]), fmaxf(s0[2], s0[3])),
                     fmaxf(fmaxf(s1[0], s1[1]), fmaxf(s1[2], s1[3])));
    tm = fmaxf(tm, fmaxf(fmaxf(fmaxf(s2[0], s2[1]), fmaxf(s2[2], s2[3])),
                         fmaxf(fmaxf(s3[0], s3[1]), fmaxf(s3[2], s3[3]))));
    tm = fmaxf(tm, __shfl_xor(tm, 16));
    tm = fmaxf(tm, __shfl_xor(tm, 32));
    rescale(tm);
    float ts = (soft_pv(s0, k0) + soft_pv(s1, k0 + 16)) +
               (soft_pv(s2, k0 + 32) + soft_pv(s3, k0 + 48));
    ts += __shfl_xor(ts, 16);
    ts += __shfl_xor(ts, 32);
    ls += ts;
  }
  // tail: k = 768..783 (fully valid 16-subtile)
  {
    f32x4 s0 = qk_subtile(768);
    float tm = fmaxf(fmaxf(s0[0], s0[1]), fmaxf(s0[2], s0[3]));
    tm = fmaxf(tm, __shfl_xor(tm, 16));
    tm = fmaxf(tm, __shfl_xor(tm, 32));
    rescale(tm);
    float ts = soft_pv(s0, 768);
    ts += __shfl_xor(ts, 16);
    ts += __shfl_xor(ts, 32);
    ls += ts;
  }

  const float inv = 1.f / ls;
  bf16* dst = ctx + qkbase + (size_t)(q0 + lr) * DM;  // token q0+lr, feature h*64+d
#pragma unroll
  for (int mt = 0; mt < 4; ++mt)
#pragma unroll
    for (int r = 0; r < 4; ++r)
      dst[mt * 16 + 4 * lq + r] = (bf16)(acc[mt][r] * inv);
}

extern "C" void kernel_launch(void* const* d_in, const int* in_sizes, int n_in,
                              void* d_out, int out_size, void* d_ws, size_t ws_size,
                              hipStream_t stream) {
  const float* x    = (const float*)d_in[0];
  const float* ln1s = (const float*)d_in[1];
  const float* ln1b = (const float*)d_in[2];
  const float* wq   = (const float*)d_in[3];
  const float* bq   = (const float*)d_in[4];
  const float* wk   = (const float*)d_in[5];
  const float* bk   = (const float*)d_in[6];
  const float* wvw  = (const float*)d_in[7];
  const float* bv   = (const float*)d_in[8];
  const float* wo   = (const float*)d_in[9];
  const float* bo   = (const float*)d_in[10];
  const float* ln2s = (const float*)d_in[11];
  const float* ln2b = (const float*)d_in[12];
  const float* w1   = (const float*)d_in[13];
  const float* b1   = (const float*)d_in[14];
  const float* w2   = (const float*)d_in[15];
  const float* b2   = (const float*)d_in[16];
  const float* lnfs = (const float*)d_in[17];
  const float* lnfb = (const float*)d_in[18];

  // ---- workspace layout (lifetime-aliased; ~81.8 MB) ----
  char* ws = (char*)d_ws;
  size_t off = 0;
  auto alloc = [&](size_t bytes) -> void* {
    void* p = ws + off;
    off += (bytes + 255) & ~(size_t)255;
    return p;
  };
  bf16* wt  = (bf16*)alloc((size_t)DM * FF * 2);       // 4.7 MB weight transpose (reused)
  float* h  = (float*)alloc((size_t)TD * DM * 4);      // 19.3 MB fp32 residual stream
  bf16* y   = (bf16*)alloc((size_t)TD * DM * 2);       // 9.6 MB LN output
  bf16* big = (bf16*)alloc((size_t)TD * DM * 5 * 2);   // 48.2 MB: qb|kb|vb|cb|vt ; mid = first 4 units
  bf16* qb   = big;
  bf16* kbuf = big + (size_t)TD * DM;
  bf16* vbuf = big + 2 * (size_t)TD * DM;
  bf16* cb   = big + 3 * (size_t)TD * DM;
  bf16* vtb  = big + 4 * (size_t)TD * DM;              // [B*H][64][784]
  bf16* mid  = big;                                    // TD*FF = 4*TD*DM, dead while qb..cb live

  const dim3 tb(32, 8);
  const dim3 gDD(DM / 32, DM / 32);
  const dim3 g768(TD / 128, DM / 128);
  const dim3 g3072(TD / 128, FF / 128);
  const dim3 gvt((SQ + 31) / 32, 2, NB * NH);
  const dim3 gattn(13, NB * NH);

  for (int l = 0; l < NL; ++l) {
    const float* wq_l = wq + (size_t)l * DM * DM;
    const float* wk_l = wk + (size_t)l * DM * DM;
    const float* wv_l = wvw + (size_t)l * DM * DM;
    const float* wo_l = wo + (size_t)l * DM * DM;
    const float* w1_l = w1 + (size_t)l * DM * FF;
    const float* w2_l = w2 + (size_t)l * FF * DM;
    const float* hin  = (l == 0) ? x : h;

    ln_kernel<bf16><<<TD, 64, 0, stream>>>(hin, ln1s + l * DM, ln1b + l * DM, y);

    transpose_kernel<<<gDD, tb, 0, stream>>>(wq_l, wt, DM, DM);
    gemm_kernel<0><<<g768, 256, 0, stream>>>(y, wt, bq + l * DM, nullptr, qb, nullptr, TD, DM, DM);
    transpose_kernel<<<gDD, tb, 0, stream>>>(wk_l, wt, DM, DM);
    gemm_kernel<0><<<g768, 256, 0, stream>>>(y, wt, bk + l * DM, nullptr, kbuf, nullptr, TD, DM, DM);
    transpose_kernel<<<gDD, tb, 0, stream>>>(wv_l, wt, DM, DM);
    gemm_kernel<0><<<g768, 256, 0, stream>>>(y, wt, bv + l * DM, nullptr, vbuf, nullptr, TD, DM, DM);

    vt_kernel<<<gvt, tb, 0, stream>>>(vbuf, vtb);
    attn_kernel<<<gattn, 256, 0, stream>>>(qb, kbuf, vtb, cb);

    transpose_kernel<<<gDD, tb, 0, stream>>>(wo_l, wt, DM, DM);
    gemm_kernel<2><<<g768, 256, 0, stream>>>(cb, wt, bo + l * DM, hin, nullptr, h, TD, DM, DM);

    ln_kernel<bf16><<<TD, 64, 0, stream>>>(h, ln2s + l * DM, ln2b + l * DM, y);

    transpose_kernel<<<dim3(FF / 32, DM / 32), tb, 0, stream>>>(w1_l, wt, DM, FF);
    gemm_kernel<1><<<g3072, 256, 0, stream>>>(y, wt, b1 + l * FF, nullptr, mid, nullptr, TD, FF, DM);
    transpose_kernel<<<dim3(DM / 32, FF / 32), tb, 0, stream>>>(w2_l, wt, FF, DM);
    gemm_kernel<2><<<g768, 256, 0, stream>>>(mid, wt, b2 + l * DM, h, nullptr, h, TD, DM, FF);
  }
  ln_kernel<float><<<TD, 64, 0, stream>>>(h, lnfs, lnfb, (float*)d_out);
}

// Round 3
// 3842.567 us; speedup vs baseline: 1.2920x; 1.2920x over previous
//
#include <hip/hip_runtime.h>
#include <cmath>

using bf16 = __bf16;
typedef short short8 __attribute__((ext_vector_type(8)));
typedef short short4v __attribute__((ext_vector_type(4)));
typedef float f32x4 __attribute__((ext_vector_type(4)));
typedef __bf16 bf16x4 __attribute__((ext_vector_type(4)));

#define TD 6272   // B*S tokens
#define DM 768
#define FF 3072
#define NL 12
#define NH 12
#define SQ 784
#define NB 8
#define QKVS 2304  // fused QKV row stride

// ---- 16x16x16 bf16 MFMA (K=16): builtin if available, else raw asm ----
#if defined(__has_builtin)
#if __has_builtin(__builtin_amdgcn_mfma_f32_16x16x16bf16_1k)
#define HAVE_MFMA16BUILTIN 1
#endif
#if __has_builtin(__builtin_amdgcn_exp2f)
#define HAVE_EXP2BUILTIN 1
#endif
#endif
static __device__ inline f32x4 mfma16x16x16_bf16(short4v a, short4v b, f32x4 c) {
#ifdef HAVE_MFMA16BUILTIN
  return __builtin_amdgcn_mfma_f32_16x16x16bf16_1k(a, b, c, 0, 0, 0);
#else
  asm volatile("v_mfma_f32_16x16x16_bf16 %0, %1, %2, %0" : "+v"(c) : "v"(a), "v"(b));
  return c;
#endif
}
static __device__ inline float exp2fast(float x) {
#ifdef HAVE_EXP2BUILTIN
  return __builtin_amdgcn_exp2f(x);
#else
  return exp2f(x);
#endif
}

// ---------- LayerNorm: fp32 in -> OutT out (one wave per token) ----------
template <typename OutT>
__global__ __launch_bounds__(64) void ln_kernel(const float* __restrict__ in,
    const float* __restrict__ s, const float* __restrict__ b, OutT* __restrict__ out) {
  const int t = blockIdx.x;
  const int lane = threadIdx.x;
  const float* row = in + (size_t)t * DM;
  float x[12];
  float sum = 0.f, sq = 0.f;
#pragma unroll
  for (int j = 0; j < 12; ++j) {
    x[j] = row[lane + 64 * j];
    sum += x[j];
    sq += x[j] * x[j];
  }
#pragma unroll
  for (int off = 32; off >= 1; off >>= 1) {
    sum += __shfl_xor(sum, off);
    sq  += __shfl_xor(sq, off);
  }
  const float mean = sum * (1.f / DM);
  const float var  = sq * (1.f / DM) - mean * mean;
  const float rstd = rsqrtf(var + 1e-6f);
  OutT* orow = out + (size_t)t * DM;
#pragma unroll
  for (int j = 0; j < 12; ++j) {
    int c = lane + 64 * j;
    orow[c] = (OutT)((x[j] - mean) * rstd * s[c] + b[c]);
  }
}

// ---------- transpose + downcast: in fp32 (R x C) -> out bf16 (C x R) ----------
__global__ void transpose_kernel(const float* __restrict__ in, bf16* __restrict__ out,
                                 int R, int C) {
  __shared__ bf16 tile[32][33];
  const int bx = blockIdx.x * 32;  // col base (in)
  const int by = blockIdx.y * 32;  // row base (in)
  const int tx = threadIdx.x, ty = threadIdx.y;  // (32, 8)
#pragma unroll
  for (int j = 0; j < 32; j += 8)
    tile[ty + j][tx] = (bf16)in[(size_t)(by + ty + j) * C + bx + tx];
  __syncthreads();
#pragma unroll
  for (int j = 0; j < 32; j += 8)
    out[(size_t)(bx + ty + j) * R + by + tx] = tile[tx][ty + j];
}

// ---------- bias concat: [bq|bk|bv] -> out[2304] ----------
__global__ void bias_concat_kernel(const float* __restrict__ bq, const float* __restrict__ bk,
                                   const float* __restrict__ bv, float* __restrict__ out) {
  const int i = blockIdx.x * 256 + threadIdx.x;
  if (i >= 3 * DM) return;
  out[i] = (i < DM) ? bq[i] : (i < 2 * DM) ? bk[i - DM] : bv[i - 2 * DM];
}

// ---------- V head-transpose: qkv [TD,2304] (V at col 1536) -> vt [B*H][64][784] ----------
__global__ void vt_kernel(const bf16* __restrict__ qkv, bf16* __restrict__ vt) {
  __shared__ bf16 tile[32][33];
  const int bh = blockIdx.z;
  const int b = bh / NH, h = bh % NH;
  const int s0 = blockIdx.x * 32, d0 = blockIdx.y * 32;
  const int tx = threadIdx.x, ty = threadIdx.y;  // (32,8)
  const bf16* src = qkv + ((size_t)b * SQ) * QKVS + 1536 + h * 64;
#pragma unroll
  for (int j = 0; j < 32; j += 8) {
    int s = s0 + ty + j;
    if (s < SQ) tile[ty + j][tx] = src[(size_t)s * QKVS + d0 + tx];
  }
  __syncthreads();
  bf16* dst = vt + (size_t)bh * 64 * SQ;
  if (s0 + tx < SQ) {
#pragma unroll
    for (int j = 0; j < 32; j += 8)
      dst[(size_t)(d0 + ty + j) * SQ + s0 + tx] = tile[tx][ty + j];
  }
}

// ---------- GEMM: C = A(MxK) * W(KxN) + bias, W given transposed Bt (NxK), bf16 MFMA ----------
// EPI 0: bias -> bf16 out ; EPI 1: bias + exact GELU -> bf16 ; EPI 2: bias + residual(fp32) -> fp32
template <int EPI>
__global__ __launch_bounds__(256) void gemm_kernel(
    const bf16* __restrict__ A, const bf16* __restrict__ Bt,
    const float* __restrict__ bias, const float* __restrict__ res,
    bf16* __restrict__ outb, float* __restrict__ outf,
    int M, int N, int K) {
  __shared__ bf16 As[128 * 32];
  __shared__ bf16 Bs[128 * 32];
  const int tid = threadIdx.x;
  const int lane = tid & 63;
  const int wid = tid >> 6;
  const size_t m0 = (size_t)blockIdx.x * 128;
  const size_t n0 = (size_t)blockIdx.y * 128;
  const int wm = (wid >> 1) * 64;
  const int wn = (wid & 1) * 64;
  const int lr = lane & 15;
  const int lq = lane >> 4;

  f32x4 acc[4][4] = {};

  const int vi0 = wid * 64 + lane;
  const int vi1 = vi0 + 256;
  const bf16* ga0 = A + (m0 + (vi0 >> 2)) * (size_t)K + (vi0 & 3) * 8;
  const bf16* ga1 = A + (m0 + (vi1 >> 2)) * (size_t)K + (vi1 & 3) * 8;
  const bf16* gb0 = Bt + (n0 + (vi0 >> 2)) * (size_t)K + (vi0 & 3) * 8;
  const bf16* gb1 = Bt + (n0 + (vi1 >> 2)) * (size_t)K + (vi1 & 3) * 8;
  bf16* la0 = As + (size_t)(wid * 64) * 8;
  bf16* la1 = As + (size_t)(wid * 64 + 256) * 8;
  bf16* lb0 = Bs + (size_t)(wid * 64) * 8;
  bf16* lb1 = Bs + (size_t)(wid * 64 + 256) * 8;

  for (int kb = 0; kb < K; kb += 32) {
    __builtin_amdgcn_global_load_lds(ga0, la0, 16, 0, 0);
    __builtin_amdgcn_global_load_lds(ga1, la1, 16, 0, 0);
    __builtin_amdgcn_global_load_lds(gb0, lb0, 16, 0, 0);
    __builtin_amdgcn_global_load_lds(gb1, lb1, 16, 0, 0);
    ga0 += 32; ga1 += 32; gb0 += 32; gb1 += 32;
    __syncthreads();
    short8 af[4], bfr[4];
#pragma unroll
    for (int t = 0; t < 4; ++t) {
      af[t]  = *(const short8*)(As + (wm + t * 16 + lr) * 32 + lq * 8);
      bfr[t] = *(const short8*)(Bs + (wn + t * 16 + lr) * 32 + lq * 8);
    }
#pragma unroll
    for (int ti = 0; ti < 4; ++ti)
#pragma unroll
      for (int tj = 0; tj < 4; ++tj)
        acc[ti][tj] = __builtin_amdgcn_mfma_f32_16x16x32_bf16(af[ti], bfr[tj], acc[ti][tj], 0, 0, 0);
    __syncthreads();
  }

#pragma unroll
  for (int ti = 0; ti < 4; ++ti) {
    const size_t row_base = m0 + wm + ti * 16 + lq * 4;
#pragma unroll
    for (int tj = 0; tj < 4; ++tj) {
      const size_t col = n0 + wn + tj * 16 + lr;
      const float bsv = bias[col];
#pragma unroll
      for (int r = 0; r < 4; ++r) {
        const size_t idx = (row_base + r) * (size_t)N + col;
        float vacc = acc[ti][tj][r] + bsv;
        if constexpr (EPI == 1) vacc = 0.5f * vacc * (1.0f + erff(vacc * 0.70710678118654752f));
        if constexpr (EPI == 2) {
          outf[idx] = res[idx] + vacc;
        } else {
          outb[idx] = (bf16)vacc;
        }
      }
    }
  }
}

// ---------- MFMA flash attention, LDS-staged KVBLK=64, double-buffered ----------
// 4 waves/block share one head's K/V via LDS (they were each re-fetching identical data).
// Per 64-k step: stage(next) via 4x global_load_lds(16B, coalesced 128B rows, XOR-swizzled
// source) -> compute(cur): 8 ds_read_b128 K + 8 QK^T MFMA -> one softmax pass (deferred
// rescale) -> 16 ds_read_b64 V + 16 PV MFMA -> barrier. Swizzle: 16B-block ^= (row&7), LDS
// dest linear, source pre-swizzled (guide rule 21). Exact XCD swizzle: 156 blocks/XCD = 12
// heads x 13 qblocks, so each head's K/V stays in one XCD's L2.
// Tail (k=768..783) via registers from global, as before. 784 = 12*64 + 16.
__global__ __launch_bounds__(256, 4) void attn_kernel(const bf16* __restrict__ qkv,
    const bf16* __restrict__ vt, bf16* __restrict__ ctx) {
  __shared__ bf16 Ks[2 * 64 * 64];   // [buf][k-row][d] (16B blocks XOR-swizzled by row&7)
  __shared__ bf16 Vs[2 * 64 * 64];   // [buf][d-row][k] (same swizzle)
  const int tid = threadIdx.x;
  const int wid = tid >> 6, lane = tid & 63;
  const int lr = lane & 15, lq = lane >> 4;
  const int r7 = lr & 7;

  // exact bijective XCD swizzle: 1248 blocks = 8 XCDs * (12 heads * 13 qblocks)
  const int wgid = blockIdx.y * gridDim.x + blockIdx.x;
  const int xcd = wgid & 7;
  const int j = wgid >> 3;            // 0..155
  const int bh = xcd * 12 + j / 13;
  const int qblk = j % 13;
  const int b = bh / NH, h = bh % NH;
  const int qt = qblk * 4 + wid;      // query tile 0..48 (49 tiles of 16)
  const bool active = (qt < 49);
  const int q0 = qt * 16;

  const bf16* qhead = qkv + (size_t)b * SQ * QKVS + h * 64;
  const bf16* khead = qhead + 768;
  const bf16* vtb = vt + (size_t)bh * 64 * SQ;

  short8 qf0 = {}, qf1 = {};
  if (active) {
    const bf16* qrow = qhead + (size_t)(q0 + lr) * QKVS + lq * 8;
    qf0 = *(const short8*)(qrow);        // B-frag: Q[q0+lr][8lq..+7]
    qf1 = *(const short8*)(qrow + 32);   //          d+32
  }

  // ---- staging bases: issue covers rows (tid>>3), 16B-chunk (tid&7), swizzled source ----
  const int sr = tid >> 3;             // 0..31 (issue 1 adds 32; (sr+32)&7 == sr&7)
  const int sc = tid & 7;
  const int scs = sc ^ (sr & 7);
  const bf16* kg = khead + (size_t)sr * QKVS + (scs << 3);
  const bf16* vg = vtb + (size_t)sr * SQ + (scs << 3);
  bf16* lkd = Ks + (wid << 9);         // wave-uniform dest; HW adds lane*16B
  bf16* lvd = Vs + (wid << 9);

  auto stage = [&](int bufi, int k0) {
    const bf16* ks = kg + (size_t)k0 * QKVS;
    const bf16* vs = vg + k0;
    bf16* lk = lkd + (bufi << 12);
    bf16* lv = lvd + (bufi << 12);
    __builtin_amdgcn_global_load_lds(ks, lk, 16, 0, 0);
    __builtin_amdgcn_global_load_lds(ks + (size_t)32 * QKVS, lk + 2048, 16, 0, 0);
    __builtin_amdgcn_global_load_lds(vs, lv, 16, 0, 0);
    __builtin_amdgcn_global_load_lds(vs + (size_t)32 * SQ, lv + 2048, 16, 0, 0);
  };

  f32x4 acc[4] = {};            // ctx^T m-tiles (d 0-15,16-31,32-47,48-63)
  float mb = -1e30f;            // running max in (score*scale*log2e) domain, col q
  float ls = 0.f;
  const float c2 = 0.125f * 1.44269504088896f;  // 1/sqrt(64) * log2(e)

  int buf = 0;
  stage(0, 0);
  __syncthreads();

  for (int kt = 0; kt < 12; ++kt) {
    if (kt < 11) stage(buf ^ 1, (kt + 1) * 64);   // prefetch overlaps compute below
    if (active) {
      const bf16* Kb = Ks + (buf << 12);
      const bf16* Vb = Vs + (buf << 12);
      f32x4 s[4];
#pragma unroll
      for (int sub = 0; sub < 4; ++sub) {
        const int row = (sub << 4) + lr;
        short8 kf0 = *(const short8*)(Kb + (row << 6) + ((lq ^ r7) << 3));
        short8 kf1 = *(const short8*)(Kb + (row << 6) + (((lq + 4) ^ r7) << 3));
        f32x4 s4 = {};
        s4 = __builtin_amdgcn_mfma_f32_16x16x32_bf16(kf0, qf0, s4, 0, 0, 0);
        s4 = __builtin_amdgcn_mfma_f32_16x16x32_bf16(kf1, qf1, s4, 0, 0, 0);
        s[sub] = s4;
      }
      float tm = s[0][0];
#pragma unroll
      for (int sub = 0; sub < 4; ++sub)
#pragma unroll
        for (int r = 0; r < 4; ++r) tm = fmaxf(tm, s[sub][r]);
      tm = fmaxf(tm, __shfl_xor(tm, 16));
      tm = fmaxf(tm, __shfl_xor(tm, 32));
      const float tmc = tm * c2;
      if (!__all(tmc <= mb + 11.5f)) {   // deferred rescale, THR = 8 nats
        const float mbn = fmaxf(mb, tmc);
        const float al = exp2fast(mb - mbn);
#pragma unroll
        for (int mt = 0; mt < 4; ++mt)
#pragma unroll
          for (int r = 0; r < 4; ++r) acc[mt][r] *= al;
        ls *= al;
        mb = mbn;
      }
      __builtin_amdgcn_s_setprio(1);
      float ts = 0.f;
#pragma unroll
      for (int sub = 0; sub < 4; ++sub) {
        float p0 = exp2fast(fmaf(s[sub][0], c2, -mb));
        float p1 = exp2fast(fmaf(s[sub][1], c2, -mb));
        float p2 = exp2fast(fmaf(s[sub][2], c2, -mb));
        float p3 = exp2fast(fmaf(s[sub][3], c2, -mb));
        bf16x4 pb;
        pb[0] = (bf16)p0; pb[1] = (bf16)p1; pb[2] = (bf16)p2; pb[3] = (bf16)p3;
        const short4v pbv = __builtin_bit_cast(short4v, pb);
        const int off = (((sub * 2 + (lq >> 1)) ^ r7) << 3) + ((lq & 1) << 2);
#pragma unroll
        for (int mt = 0; mt < 4; ++mt) {
          const int rowv = (mt << 4) + lr;
          short4v vf = *(const short4v*)(Vb + (rowv << 6) + off);
          acc[mt] = mfma16x16x16_bf16(vf, pbv, acc[mt]);
        }
        ts += (p0 + p1) + (p2 + p3);
      }
      __builtin_amdgcn_s_setprio(0);
      ts += __shfl_xor(ts, 16);
      ts += __shfl_xor(ts, 32);
      ls += ts;
    }
    __syncthreads();
    buf ^= 1;
  }

  // tail: k = 768..783, register path from global (fully valid 16-subtile)
  if (active) {
    const bf16* krow = khead + (size_t)(768 + lr) * QKVS + lq * 8;
    short8 kf0 = *(const short8*)(krow);
    short8 kf1 = *(const short8*)(krow + 32);
    f32x4 s4 = {};
    s4 = __builtin_amdgcn_mfma_f32_16x16x32_bf16(kf0, qf0, s4, 0, 0, 0);
    s4 = __builtin_amdgcn_mfma_f32_16x16x32_bf16(kf1, qf1, s4, 0, 0, 0);
    float tm = fmaxf(fmaxf(s4[0], s4[1]), fmaxf(s4[2], s4[3]));
    tm = fmaxf(tm, __shfl_xor(tm, 16));
    tm = fmaxf(tm, __shfl_xor(tm, 32));
    const float tmc = tm * c2;
    if (!__all(tmc <= mb + 11.5f)) {
      const float mbn = fmaxf(mb, tmc);
      const float al = exp2fast(mb - mbn);
#pragma unroll
      for (int mt = 0; mt < 4; ++mt)
#pragma unroll
        for (int r = 0; r < 4; ++r) acc[mt][r] *= al;
      ls *= al;
      mb = mbn;
    }
    float p0 = exp2fast(fmaf(s4[0], c2, -mb));
    float p1 = exp2fast(fmaf(s4[1], c2, -mb));
    float p2 = exp2fast(fmaf(s4[2], c2, -mb));
    float p3 = exp2fast(fmaf(s4[3], c2, -mb));
    bf16x4 pb;
    pb[0] = (bf16)p0; pb[1] = (bf16)p1; pb[2] = (bf16)p2; pb[3] = (bf16)p3;
    const short4v pbv = __builtin_bit_cast(short4v, pb);
    const bf16* vp = vtb + (size_t)lr * SQ + 4 * lq + 768;
#pragma unroll
    for (int mt = 0; mt < 4; ++mt) {
      short4v vf = *(const short4v*)(vp + (size_t)mt * 16 * SQ);
      acc[mt] = mfma16x16x16_bf16(vf, pbv, acc[mt]);
    }
    float ts = (p0 + p1) + (p2 + p3);
    ts += __shfl_xor(ts, 16);
    ts += __shfl_xor(ts, 32);
    ls += ts;

    const float inv = 1.f / ls;
    bf16* dst = ctx + ((size_t)b * SQ + q0 + lr) * DM + h * 64;  // ctx row stride = DM
#pragma unroll
    for (int mt = 0; mt < 4; ++mt)
#pragma unroll
      for (int r = 0; r < 4; ++r)
        dst[mt * 16 + 4 * lq + r] = (bf16)(acc[mt][r] * inv);
  }
}

extern "C" void kernel_launch(void* const* d_in, const int* in_sizes, int n_in,
                              void* d_out, int out_size, void* d_ws, size_t ws_size,
                              hipStream_t stream) {
  const float* x    = (const float*)d_in[0];
  const float* ln1s = (const float*)d_in[1];
  const float* ln1b = (const float*)d_in[2];
  const float* wq   = (const float*)d_in[3];
  const float* bq   = (const float*)d_in[4];
  const float* wk   = (const float*)d_in[5];
  const float* bk   = (const float*)d_in[6];
  const float* wvw  = (const float*)d_in[7];
  const float* bv   = (const float*)d_in[8];
  const float* wo   = (const float*)d_in[9];
  const float* bo   = (const float*)d_in[10];
  const float* ln2s = (const float*)d_in[11];
  const float* ln2b = (const float*)d_in[12];
  const float* w1   = (const float*)d_in[13];
  const float* b1   = (const float*)d_in[14];
  const float* w2   = (const float*)d_in[15];
  const float* b2   = (const float*)d_in[16];
  const float* lnfs = (const float*)d_in[17];
  const float* lnfb = (const float*)d_in[18];

  // ---- workspace layout (lifetime-aliased; ~81.8 MB, unchanged) ----
  char* ws = (char*)d_ws;
  size_t off = 0;
  auto alloc = [&](size_t bytes) -> void* {
    void* p = ws + off;
    off += (bytes + 255) & ~(size_t)255;
    return p;
  };
  bf16* wt  = (bf16*)alloc((size_t)DM * FF * 2);       // 4.7 MB weight transpose (reused)
  float* h  = (float*)alloc((size_t)TD * DM * 4);      // 19.3 MB fp32 residual stream
  bf16* y   = (bf16*)alloc((size_t)TD * DM * 2);       // 9.6 MB LN output
  bf16* big = (bf16*)alloc((size_t)TD * DM * 5 * 2);   // 48.2 MB: qkv(3u)|cb|vt ; mid = first 4 units
  bf16* qkv  = big;                                    // [TD][2304] fused Q|K|V
  bf16* cb   = big + 3 * (size_t)TD * DM;
  bf16* vtb  = big + 4 * (size_t)TD * DM;              // [B*H][64][784]
  bf16* mid  = big;                                    // TD*FF = 4*TD*DM, dead while qkv/cb live
  // bias concat buffer: carved from tail of wt region (QKV transpose uses only 3.54 MB of it)
  float* bcat = (float*)((char*)wt + (size_t)DM * FF * 2 - 16384);

  const dim3 tb(32, 8);
  const dim3 gDD(DM / 32, DM / 32);
  const dim3 g768(TD / 128, DM / 128);
  const dim3 gqkv(TD / 128, QKVS / 128);
  const dim3 g3072(TD / 128, FF / 128);
  const dim3 gvt((SQ + 31) / 32, 2, NB * NH);
  const dim3 gattn(13, NB * NH);

  for (int l = 0; l < NL; ++l) {
    const float* wq_l = wq + (size_t)l * DM * DM;
    const float* wk_l = wk + (size_t)l * DM * DM;
    const float* wv_l = wvw + (size_t)l * DM * DM;
    const float* wo_l = wo + (size_t)l * DM * DM;
    const float* w1_l = w1 + (size_t)l * DM * FF;
    const float* w2_l = w2 + (size_t)l * FF * DM;
    const float* hin  = (l == 0) ? x : h;

    ln_kernel<bf16><<<TD, 64, 0, stream>>>(hin, ln1s + l * DM, ln1b + l * DM, y);

    // fused QKV: wt rows [0,768)=Wq^T, [768,1536)=Wk^T, [1536,2304)=Wv^T
    transpose_kernel<<<gDD, tb, 0, stream>>>(wq_l, wt, DM, DM);
    transpose_kernel<<<gDD, tb, 0, stream>>>(wk_l, wt + (size_t)DM * DM, DM, DM);
    transpose_kernel<<<gDD, tb, 0, stream>>>(wv_l, wt + 2 * (size_t)DM * DM, DM, DM);
    bias_concat_kernel<<<9, 256, 0, stream>>>(bq + l * DM, bk + l * DM, bv + l * DM, bcat);
    gemm_kernel<0><<<gqkv, 256, 0, stream>>>(y, wt, bcat, nullptr, qkv, nullptr, TD, QKVS, DM);

    vt_kernel<<<gvt, tb, 0, stream>>>(qkv, vtb);
    attn_kernel<<<gattn, 256, 0, stream>>>(qkv, vtb, cb);

    transpose_kernel<<<gDD, tb, 0, stream>>>(wo_l, wt, DM, DM);
    gemm_kernel<2><<<g768, 256, 0, stream>>>(cb, wt, bo + l * DM, hin, nullptr, h, TD, DM, DM);

    ln_kernel<bf16><<<TD, 64, 0, stream>>>(h, ln2s + l * DM, ln2b + l * DM, y);

    transpose_kernel<<<dim3(FF / 32, DM / 32), tb, 0, stream>>>(w1_l, wt, DM, FF);
    gemm_kernel<1><<<g3072, 256, 0, stream>>>(y, wt, b1 + l * FF, nullptr, mid, nullptr, TD, FF, DM);
    transpose_kernel<<<dim3(DM / 32, FF / 32), tb, 0, stream>>>(w2_l, wt, FF, DM);
    gemm_kernel<2><<<g768, 256, 0, stream>>>(mid, wt, b2 + l * DM, h, nullptr, h, TD, DM, FF);
  }
  ln_kernel<float><<<TD, 64, 0, stream>>>(h, lnfs, lnfb, (float*)d_out);
}

// Round 4
// 3603.121 us; speedup vs baseline: 1.3779x; 1.0665x over previous
//
#include <hip/hip_runtime.h>
#include <cmath>

using bf16 = __bf16;
typedef short short8 __attribute__((ext_vector_type(8)));
typedef short short4v __attribute__((ext_vector_type(4)));
typedef float f32x4 __attribute__((ext_vector_type(4)));
typedef __bf16 bf16x4 __attribute__((ext_vector_type(4)));

#define TD 6272   // B*S tokens
#define DM 768
#define FF 3072
#define NL 12
#define NH 12
#define SQ 784
#define NB 8
#define QKVS 2304  // fused QKV row stride

// ---- 16x16x16 bf16 MFMA (K=16): builtin if available, else raw asm ----
#if defined(__has_builtin)
#if __has_builtin(__builtin_amdgcn_mfma_f32_16x16x16bf16_1k)
#define HAVE_MFMA16BUILTIN 1
#endif
#if __has_builtin(__builtin_amdgcn_exp2f)
#define HAVE_EXP2BUILTIN 1
#endif
#endif
static __device__ inline f32x4 mfma16x16x16_bf16(short4v a, short4v b, f32x4 c) {
#ifdef HAVE_MFMA16BUILTIN
  return __builtin_amdgcn_mfma_f32_16x16x16bf16_1k(a, b, c, 0, 0, 0);
#else
  asm volatile("v_mfma_f32_16x16x16_bf16 %0, %1, %2, %0" : "+v"(c) : "v"(a), "v"(b));
  return c;
#endif
}
static __device__ inline float exp2fast(float x) {
#ifdef HAVE_EXP2BUILTIN
  return __builtin_amdgcn_exp2f(x);
#else
  return exp2f(x);
#endif
}

// ---------- LayerNorm: fp32 in -> OutT out (one wave per token) ----------
template <typename OutT>
__global__ __launch_bounds__(64) void ln_kernel(const float* __restrict__ in,
    const float* __restrict__ s, const float* __restrict__ b, OutT* __restrict__ out) {
  const int t = blockIdx.x;
  const int lane = threadIdx.x;
  const float* row = in + (size_t)t * DM;
  float x[12];
  float sum = 0.f, sq = 0.f;
#pragma unroll
  for (int j = 0; j < 12; ++j) {
    x[j] = row[lane + 64 * j];
    sum += x[j];
    sq += x[j] * x[j];
  }
#pragma unroll
  for (int off = 32; off >= 1; off >>= 1) {
    sum += __shfl_xor(sum, off);
    sq  += __shfl_xor(sq, off);
  }
  const float mean = sum * (1.f / DM);
  const float var  = sq * (1.f / DM) - mean * mean;
  const float rstd = rsqrtf(var + 1e-6f);
  OutT* orow = out + (size_t)t * DM;
#pragma unroll
  for (int j = 0; j < 12; ++j) {
    int c = lane + 64 * j;
    orow[c] = (OutT)((x[j] - mean) * rstd * s[c] + b[c]);
  }
}

// ---------- transpose + downcast: in fp32 (R x C) -> out bf16 (C x R) ----------
__global__ void transpose_kernel(const float* __restrict__ in, bf16* __restrict__ out,
                                 int R, int C) {
  __shared__ bf16 tile[32][33];
  const int bx = blockIdx.x * 32;  // col base (in)
  const int by = blockIdx.y * 32;  // row base (in)
  const int tx = threadIdx.x, ty = threadIdx.y;  // (32, 8)
#pragma unroll
  for (int j = 0; j < 32; j += 8)
    tile[ty + j][tx] = (bf16)in[(size_t)(by + ty + j) * C + bx + tx];
  __syncthreads();
#pragma unroll
  for (int j = 0; j < 32; j += 8)
    out[(size_t)(bx + ty + j) * R + by + tx] = tile[tx][ty + j];
}

// ---------- fused QKV+WO weight transpose + bias concat (saves 4 launches/layer) ----------
// tiles 0..575 wq -> wt[0,768); 576..1151 wk; 1152..1727 wv; 1728..2303 wo -> wt+3*768^2
// block 2304: bcat[2304] = [bq|bk|bv]
__global__ void qkv_prep_kernel(const float* __restrict__ wq, const float* __restrict__ wk,
    const float* __restrict__ wv, const float* __restrict__ wo,
    const float* __restrict__ bq, const float* __restrict__ bk, const float* __restrict__ bv,
    bf16* __restrict__ wt, float* __restrict__ bcat) {
  const int t = blockIdx.x;
  const int tx = threadIdx.x, ty = threadIdx.y;  // (32,8)
  if (t >= 2304) {
    const int i = ty * 32 + tx;
    for (int j = i; j < 3 * DM; j += 256)
      bcat[j] = (j < DM) ? bq[j] : (j < 2 * DM) ? bk[j - DM] : bv[j - 2 * DM];
    return;
  }
  const int m = t / 576, tile_id = t % 576;
  const float* src = (m == 0) ? wq : (m == 1) ? wk : (m == 2) ? wv : wo;
  bf16* dst = wt + (size_t)m * DM * DM;
  const int bx = (tile_id % 24) * 32, by = (tile_id / 24) * 32;
  __shared__ bf16 tile[32][33];
#pragma unroll
  for (int j = 0; j < 32; j += 8)
    tile[ty + j][tx] = (bf16)src[(size_t)(by + ty + j) * DM + bx + tx];
  __syncthreads();
#pragma unroll
  for (int j = 0; j < 32; j += 8)
    dst[(size_t)(bx + ty + j) * DM + by + tx] = tile[tx][ty + j];
}

// ---------- V head-transpose: qkv [TD,2304] (V at col 1536) -> vt [B*H][64][784] ----------
__global__ void vt_kernel(const bf16* __restrict__ qkv, bf16* __restrict__ vt) {
  __shared__ bf16 tile[32][33];
  const int bh = blockIdx.z;
  const int b = bh / NH, h = bh % NH;
  const int s0 = blockIdx.x * 32, d0 = blockIdx.y * 32;
  const int tx = threadIdx.x, ty = threadIdx.y;  // (32,8)
  const bf16* src = qkv + ((size_t)b * SQ) * QKVS + 1536 + h * 64;
#pragma unroll
  for (int j = 0; j < 32; j += 8) {
    int s = s0 + ty + j;
    if (s < SQ) tile[ty + j][tx] = src[(size_t)s * QKVS + d0 + tx];
  }
  __syncthreads();
  bf16* dst = vt + (size_t)bh * 64 * SQ;
  if (s0 + tx < SQ) {
#pragma unroll
    for (int j = 0; j < 32; j += 8)
      dst[(size_t)(d0 + ty + j) * SQ + s0 + tx] = tile[tx][ty + j];
  }
}

// ---------- GEMM 128x128: C = A(MxK) * W(KxN) + bias, W transposed Bt (NxK) ----------
// LDS chunk-XOR swizzle (T2, BK=32): slot (row, c) holds global chunk c ^ ((row>>1)&3);
// reader uses chunk lq ^ ((lr>>1)&3) -> 2-way banks (free, m136). Source pre-swizzled,
// LDS dest linear (guide rule 21).
// EPI 0: bias -> bf16 ; EPI 1: bias + exact GELU -> bf16 ; EPI 2: bias + residual -> fp32
template <int EPI>
__global__ __launch_bounds__(256) void gemm_kernel(
    const bf16* __restrict__ A, const bf16* __restrict__ Bt,
    const float* __restrict__ bias, const float* __restrict__ res,
    bf16* __restrict__ outb, float* __restrict__ outf,
    int M, int N, int K) {
  __shared__ bf16 As[128 * 32];
  __shared__ bf16 Bs[128 * 32];
  const int tid = threadIdx.x;
  const int lane = tid & 63;
  const int wid = tid >> 6;
  const size_t m0 = (size_t)blockIdx.x * 128;
  const size_t n0 = (size_t)blockIdx.y * 128;
  const int wm = (wid >> 1) * 64;
  const int wn = (wid & 1) * 64;
  const int lr = lane & 15;
  const int lq = lane >> 4;
  const int sw = (lr >> 1) & 3;   // read-side swizzle

  f32x4 acc[4][4] = {};

  const int vi0 = wid * 64 + lane;           // slot 0..255 -> rows 0..63
  const int r0 = vi0 >> 2, c0 = vi0 & 3;
  const int cs0 = c0 ^ ((r0 >> 1) & 3);      // rows 64..127 have same swizzle value
  const bf16* ga0 = A + (m0 + r0) * (size_t)K + cs0 * 8;
  const bf16* ga1 = ga0 + (size_t)64 * K;
  const bf16* gb0 = Bt + (n0 + r0) * (size_t)K + cs0 * 8;
  const bf16* gb1 = gb0 + (size_t)64 * K;
  bf16* la0 = As + (size_t)(wid * 64) * 8;
  bf16* la1 = As + (size_t)(wid * 64 + 256) * 8;
  bf16* lb0 = Bs + (size_t)(wid * 64) * 8;
  bf16* lb1 = Bs + (size_t)(wid * 64 + 256) * 8;

  for (int kb = 0; kb < K; kb += 32) {
    __builtin_amdgcn_global_load_lds(ga0, la0, 16, 0, 0);
    __builtin_amdgcn_global_load_lds(ga1, la1, 16, 0, 0);
    __builtin_amdgcn_global_load_lds(gb0, lb0, 16, 0, 0);
    __builtin_amdgcn_global_load_lds(gb1, lb1, 16, 0, 0);
    ga0 += 32; ga1 += 32; gb0 += 32; gb1 += 32;
    __syncthreads();
    short8 af[4], bfr[4];
#pragma unroll
    for (int t = 0; t < 4; ++t) {
      af[t]  = *(const short8*)(As + (wm + t * 16 + lr) * 32 + ((lq ^ sw) << 3));
      bfr[t] = *(const short8*)(Bs + (wn + t * 16 + lr) * 32 + ((lq ^ sw) << 3));
    }
#pragma unroll
    for (int ti = 0; ti < 4; ++ti)
#pragma unroll
      for (int tj = 0; tj < 4; ++tj)
        acc[ti][tj] = __builtin_amdgcn_mfma_f32_16x16x32_bf16(af[ti], bfr[tj], acc[ti][tj], 0, 0, 0);
    __syncthreads();
  }

#pragma unroll
  for (int ti = 0; ti < 4; ++ti) {
    const size_t row_base = m0 + wm + ti * 16 + lq * 4;
#pragma unroll
    for (int tj = 0; tj < 4; ++tj) {
      const size_t col = n0 + wn + tj * 16 + lr;
      const float bsv = bias[col];
#pragma unroll
      for (int r = 0; r < 4; ++r) {
        const size_t idx = (row_base + r) * (size_t)N + col;
        float vacc = acc[ti][tj][r] + bsv;
        if constexpr (EPI == 1) vacc = 0.5f * vacc * (1.0f + erff(vacc * 0.70710678118654752f));
        if constexpr (EPI == 2) {
          outf[idx] = res[idx] + vacc;
        } else {
          outb[idx] = (bf16)vacc;
        }
      }
    }
  }
}

// ---------- GEMM 64x64 tile for skinny-N (N=768) outputs: 1176 blocks vs 294 ----------
// Fixes the 11% occupancy of FF2/WO (1.15 blocks/CU with 128^2): 4.6 blocks/CU, ~18
// waves/CU -> cross-block overlap hides barrier drains (m114 mechanism). Same swizzle.
template <int EPI>
__global__ __launch_bounds__(256, 4) void gemm64_kernel(
    const bf16* __restrict__ A, const bf16* __restrict__ Bt,
    const float* __restrict__ bias, const float* __restrict__ res,
    bf16* __restrict__ outb, float* __restrict__ outf,
    int M, int N, int K) {
  __shared__ bf16 As[64 * 32];
  __shared__ bf16 Bs[64 * 32];
  const int tid = threadIdx.x;
  const int lane = tid & 63;
  const int wid = tid >> 6;
  const size_t m0 = (size_t)blockIdx.x * 64;
  const size_t n0 = (size_t)blockIdx.y * 64;
  const int wm = (wid >> 1) * 32;
  const int wn = (wid & 1) * 32;
  const int lr = lane & 15;
  const int lq = lane >> 4;
  const int sw = (lr >> 1) & 3;

  f32x4 acc[2][2] = {};

  const int r0 = tid >> 2, c0 = tid & 3;     // slot=tid covers all 64 rows x 4 chunks
  const int cs0 = c0 ^ ((r0 >> 1) & 3);
  const bf16* ga = A + (m0 + r0) * (size_t)K + cs0 * 8;
  const bf16* gb = Bt + (n0 + r0) * (size_t)K + cs0 * 8;
  bf16* la = As + (size_t)wid * 512;
  bf16* lb = Bs + (size_t)wid * 512;

  for (int kb = 0; kb < K; kb += 32) {
    __builtin_amdgcn_global_load_lds(ga, la, 16, 0, 0);
    __builtin_amdgcn_global_load_lds(gb, lb, 16, 0, 0);
    ga += 32; gb += 32;
    __syncthreads();
    short8 af[2], bfr[2];
#pragma unroll
    for (int t = 0; t < 2; ++t) {
      af[t]  = *(const short8*)(As + (wm + t * 16 + lr) * 32 + ((lq ^ sw) << 3));
      bfr[t] = *(const short8*)(Bs + (wn + t * 16 + lr) * 32 + ((lq ^ sw) << 3));
    }
#pragma unroll
    for (int ti = 0; ti < 2; ++ti)
#pragma unroll
      for (int tj = 0; tj < 2; ++tj)
        acc[ti][tj] = __builtin_amdgcn_mfma_f32_16x16x32_bf16(af[ti], bfr[tj], acc[ti][tj], 0, 0, 0);
    __syncthreads();
  }

#pragma unroll
  for (int ti = 0; ti < 2; ++ti) {
    const size_t row_base = m0 + wm + ti * 16 + lq * 4;
#pragma unroll
    for (int tj = 0; tj < 2; ++tj) {
      const size_t col = n0 + wn + tj * 16 + lr;
      const float bsv = bias[col];
#pragma unroll
      for (int r = 0; r < 4; ++r) {
        const size_t idx = (row_base + r) * (size_t)N + col;
        float vacc = acc[ti][tj][r] + bsv;
        if constexpr (EPI == 1) vacc = 0.5f * vacc * (1.0f + erff(vacc * 0.70710678118654752f));
        if constexpr (EPI == 2) {
          outf[idx] = res[idx] + vacc;
        } else {
          outb[idx] = (bf16)vacc;
        }
      }
    }
  }
}

// ---------- MFMA flash attention, LDS-staged KVBLK=64, double-buffered (unchanged) ----------
__global__ __launch_bounds__(256, 4) void attn_kernel(const bf16* __restrict__ qkv,
    const bf16* __restrict__ vt, bf16* __restrict__ ctx) {
  __shared__ bf16 Ks[2 * 64 * 64];   // [buf][k-row][d] (16B blocks XOR-swizzled by row&7)
  __shared__ bf16 Vs[2 * 64 * 64];   // [buf][d-row][k] (same swizzle)
  const int tid = threadIdx.x;
  const int wid = tid >> 6, lane = tid & 63;
  const int lr = lane & 15, lq = lane >> 4;
  const int r7 = lr & 7;

  // exact bijective XCD swizzle: 1248 blocks = 8 XCDs * (12 heads * 13 qblocks)
  const int wgid = blockIdx.y * gridDim.x + blockIdx.x;
  const int xcd = wgid & 7;
  const int j = wgid >> 3;            // 0..155
  const int bh = xcd * 12 + j / 13;
  const int qblk = j % 13;
  const int b = bh / NH, h = bh % NH;
  const int qt = qblk * 4 + wid;      // query tile 0..48 (49 tiles of 16)
  const bool active = (qt < 49);
  const int q0 = qt * 16;

  const bf16* qhead = qkv + (size_t)b * SQ * QKVS + h * 64;
  const bf16* khead = qhead + 768;
  const bf16* vtb = vt + (size_t)bh * 64 * SQ;

  short8 qf0 = {}, qf1 = {};
  if (active) {
    const bf16* qrow = qhead + (size_t)(q0 + lr) * QKVS + lq * 8;
    qf0 = *(const short8*)(qrow);        // B-frag: Q[q0+lr][8lq..+7]
    qf1 = *(const short8*)(qrow + 32);   //          d+32
  }

  // ---- staging bases: rows (tid>>3), 16B-chunk (tid&7), swizzled source ----
  const int sr = tid >> 3;             // 0..31 (issue 1 adds 32; (sr+32)&7 == sr&7)
  const int sc = tid & 7;
  const int scs = sc ^ (sr & 7);
  const bf16* kg = khead + (size_t)sr * QKVS + (scs << 3);
  const bf16* vg = vtb + (size_t)sr * SQ + (scs << 3);
  bf16* lkd = Ks + (wid << 9);         // wave-uniform dest; HW adds lane*16B
  bf16* lvd = Vs + (wid << 9);

  auto stage = [&](int bufi, int k0) {
    const bf16* ks = kg + (size_t)k0 * QKVS;
    const bf16* vs = vg + k0;
    bf16* lk = lkd + (bufi << 12);
    bf16* lv = lvd + (bufi << 12);
    __builtin_amdgcn_global_load_lds(ks, lk, 16, 0, 0);
    __builtin_amdgcn_global_load_lds(ks + (size_t)32 * QKVS, lk + 2048, 16, 0, 0);
    __builtin_amdgcn_global_load_lds(vs, lv, 16, 0, 0);
    __builtin_amdgcn_global_load_lds(vs + (size_t)32 * SQ, lv + 2048, 16, 0, 0);
  };

  f32x4 acc[4] = {};            // ctx^T m-tiles (d 0-15,16-31,32-47,48-63)
  float mb = -1e30f;            // running max in (score*scale*log2e) domain, col q
  float ls = 0.f;
  const float c2 = 0.125f * 1.44269504088896f;  // 1/sqrt(64) * log2(e)

  int buf = 0;
  stage(0, 0);
  __syncthreads();

  for (int kt = 0; kt < 12; ++kt) {
    if (kt < 11) stage(buf ^ 1, (kt + 1) * 64);   // prefetch overlaps compute below
    if (active) {
      const bf16* Kb = Ks + (buf << 12);
      const bf16* Vb = Vs + (buf << 12);
      f32x4 s[4];
#pragma unroll
      for (int sub = 0; sub < 4; ++sub) {
        const int row = (sub << 4) + lr;
        short8 kf0 = *(const short8*)(Kb + (row << 6) + ((lq ^ r7) << 3));
        short8 kf1 = *(const short8*)(Kb + (row << 6) + (((lq + 4) ^ r7) << 3));
        f32x4 s4 = {};
        s4 = __builtin_amdgcn_mfma_f32_16x16x32_bf16(kf0, qf0, s4, 0, 0, 0);
        s4 = __builtin_amdgcn_mfma_f32_16x16x32_bf16(kf1, qf1, s4, 0, 0, 0);
        s[sub] = s4;
      }
      float tm = s[0][0];
#pragma unroll
      for (int sub = 0; sub < 4; ++sub)
#pragma unroll
        for (int r = 0; r < 4; ++r) tm = fmaxf(tm, s[sub][r]);
      tm = fmaxf(tm, __shfl_xor(tm, 16));
      tm = fmaxf(tm, __shfl_xor(tm, 32));
      const float tmc = tm * c2;
      if (!__all(tmc <= mb + 11.5f)) {   // deferred rescale, THR = 8 nats
        const float mbn = fmaxf(mb, tmc);
        const float al = exp2fast(mb - mbn);
#pragma unroll
        for (int mt = 0; mt < 4; ++mt)
#pragma unroll
          for (int r = 0; r < 4; ++r) acc[mt][r] *= al;
        ls *= al;
        mb = mbn;
      }
      __builtin_amdgcn_s_setprio(1);
      float ts = 0.f;
#pragma unroll
      for (int sub = 0; sub < 4; ++sub) {
        float p0 = exp2fast(fmaf(s[sub][0], c2, -mb));
        float p1 = exp2fast(fmaf(s[sub][1], c2, -mb));
        float p2 = exp2fast(fmaf(s[sub][2], c2, -mb));
        float p3 = exp2fast(fmaf(s[sub][3], c2, -mb));
        bf16x4 pb;
        pb[0] = (bf16)p0; pb[1] = (bf16)p1; pb[2] = (bf16)p2; pb[3] = (bf16)p3;
        const short4v pbv = __builtin_bit_cast(short4v, pb);
        const int off = (((sub * 2 + (lq >> 1)) ^ r7) << 3) + ((lq & 1) << 2);
#pragma unroll
        for (int mt = 0; mt < 4; ++mt) {
          const int rowv = (mt << 4) + lr;
          short4v vf = *(const short4v*)(Vb + (rowv << 6) + off);
          acc[mt] = mfma16x16x16_bf16(vf, pbv, acc[mt]);
        }
        ts += (p0 + p1) + (p2 + p3);
      }
      __builtin_amdgcn_s_setprio(0);
      ts += __shfl_xor(ts, 16);
      ts += __shfl_xor(ts, 32);
      ls += ts;
    }
    __syncthreads();
    buf ^= 1;
  }

  // tail: k = 768..783, register path from global (fully valid 16-subtile)
  if (active) {
    const bf16* krow = khead + (size_t)(768 + lr) * QKVS + lq * 8;
    short8 kf0 = *(const short8*)(krow);
    short8 kf1 = *(const short8*)(krow + 32);
    f32x4 s4 = {};
    s4 = __builtin_amdgcn_mfma_f32_16x16x32_bf16(kf0, qf0, s4, 0, 0, 0);
    s4 = __builtin_amdgcn_mfma_f32_16x16x32_bf16(kf1, qf1, s4, 0, 0, 0);
    float tm = fmaxf(fmaxf(s4[0], s4[1]), fmaxf(s4[2], s4[3]));
    tm = fmaxf(tm, __shfl_xor(tm, 16));
    tm = fmaxf(tm, __shfl_xor(tm, 32));
    const float tmc = tm * c2;
    if (!__all(tmc <= mb + 11.5f)) {
      const float mbn = fmaxf(mb, tmc);
      const float al = exp2fast(mb - mbn);
#pragma unroll
      for (int mt = 0; mt < 4; ++mt)
#pragma unroll
        for (int r = 0; r < 4; ++r) acc[mt][r] *= al;
      ls *= al;
      mb = mbn;
    }
    float p0 = exp2fast(fmaf(s4[0], c2, -mb));
    float p1 = exp2fast(fmaf(s4[1], c2, -mb));
    float p2 = exp2fast(fmaf(s4[2], c2, -mb));
    float p3 = exp2fast(fmaf(s4[3], c2, -mb));
    bf16x4 pb;
    pb[0] = (bf16)p0; pb[1] = (bf16)p1; pb[2] = (bf16)p2; pb[3] = (bf16)p3;
    const short4v pbv = __builtin_bit_cast(short4v, pb);
    const bf16* vp = vtb + (size_t)lr * SQ + 4 * lq + 768;
#pragma unroll
    for (int mt = 0; mt < 4; ++mt) {
      short4v vf = *(const short4v*)(vp + (size_t)mt * 16 * SQ);
      acc[mt] = mfma16x16x16_bf16(vf, pbv, acc[mt]);
    }
    float ts = (p0 + p1) + (p2 + p3);
    ts += __shfl_xor(ts, 16);
    ts += __shfl_xor(ts, 32);
    ls += ts;

    const float inv = 1.f / ls;
    bf16* dst = ctx + ((size_t)b * SQ + q0 + lr) * DM + h * 64;  // ctx row stride = DM
#pragma unroll
    for (int mt = 0; mt < 4; ++mt)
#pragma unroll
      for (int r = 0; r < 4; ++r)
        dst[mt * 16 + 4 * lq + r] = (bf16)(acc[mt][r] * inv);
  }
}

extern "C" void kernel_launch(void* const* d_in, const int* in_sizes, int n_in,
                              void* d_out, int out_size, void* d_ws, size_t ws_size,
                              hipStream_t stream) {
  const float* x    = (const float*)d_in[0];
  const float* ln1s = (const float*)d_in[1];
  const float* ln1b = (const float*)d_in[2];
  const float* wq   = (const float*)d_in[3];
  const float* bq   = (const float*)d_in[4];
  const float* wk   = (const float*)d_in[5];
  const float* bk   = (const float*)d_in[6];
  const float* wvw  = (const float*)d_in[7];
  const float* bv   = (const float*)d_in[8];
  const float* wo   = (const float*)d_in[9];
  const float* bo   = (const float*)d_in[10];
  const float* ln2s = (const float*)d_in[11];
  const float* ln2b = (const float*)d_in[12];
  const float* w1   = (const float*)d_in[13];
  const float* b1   = (const float*)d_in[14];
  const float* w2   = (const float*)d_in[15];
  const float* b2   = (const float*)d_in[16];
  const float* lnfs = (const float*)d_in[17];
  const float* lnfb = (const float*)d_in[18];

  // ---- workspace layout (lifetime-aliased; ~81.8 MB, unchanged) ----
  char* ws = (char*)d_ws;
  size_t off = 0;
  auto alloc = [&](size_t bytes) -> void* {
    void* p = ws + off;
    off += (bytes + 255) & ~(size_t)255;
    return p;
  };
  bf16* wt  = (bf16*)alloc((size_t)DM * FF * 2);       // 4.7 MB weight transpose (reused)
  float* h  = (float*)alloc((size_t)TD * DM * 4);      // 19.3 MB fp32 residual stream
  bf16* y   = (bf16*)alloc((size_t)TD * DM * 2);       // 9.6 MB LN output
  bf16* big = (bf16*)alloc((size_t)TD * DM * 5 * 2);   // 48.2 MB: qkv(3u)|cb|vt ; mid = first 4 units
  bf16* qkv  = big;                                    // [TD][2304] fused Q|K|V
  bf16* cb   = big + 3 * (size_t)TD * DM;
  bf16* vtb  = big + 4 * (size_t)TD * DM;              // [B*H][64][784]
  bf16* mid  = big;                                    // TD*FF = 4*TD*DM, dead while qkv/cb live
  // bcat: carved from vtb start (disjoint lifetimes: bcat live [prep, QKV gemm];
  // vtb written by vt_kernel strictly after the QKV gemm completes)
  float* bcat = (float*)vtb;

  const dim3 tb(32, 8);
  const dim3 gqkv(TD / 128, QKVS / 128);
  const dim3 g3072(TD / 128, FF / 128);
  const dim3 g64(TD / 64, DM / 64);
  const dim3 gvt((SQ + 31) / 32, 2, NB * NH);
  const dim3 gattn(13, NB * NH);

  for (int l = 0; l < NL; ++l) {
    const float* wq_l = wq + (size_t)l * DM * DM;
    const float* wk_l = wk + (size_t)l * DM * DM;
    const float* wv_l = wvw + (size_t)l * DM * DM;
    const float* wo_l = wo + (size_t)l * DM * DM;
    const float* w1_l = w1 + (size_t)l * DM * FF;
    const float* w2_l = w2 + (size_t)l * FF * DM;
    const float* hin  = (l == 0) ? x : h;

    ln_kernel<bf16><<<TD, 64, 0, stream>>>(hin, ln1s + l * DM, ln1b + l * DM, y);

    // one fused prep: wt rows [0,768)=Wq^T [768,1536)=Wk^T [1536,2304)=Wv^T, +3*DM^2=Wo^T, bcat
    qkv_prep_kernel<<<2305, tb, 0, stream>>>(wq_l, wk_l, wv_l, wo_l,
                                             bq + l * DM, bk + l * DM, bv + l * DM, wt, bcat);
    gemm_kernel<0><<<gqkv, 256, 0, stream>>>(y, wt, bcat, nullptr, qkv, nullptr, TD, QKVS, DM);

    vt_kernel<<<gvt, tb, 0, stream>>>(qkv, vtb);
    attn_kernel<<<gattn, 256, 0, stream>>>(qkv, vtb, cb);

    gemm64_kernel<2><<<g64, 256, 0, stream>>>(cb, wt + 3 * (size_t)DM * DM, bo + l * DM,
                                              hin, nullptr, h, TD, DM, DM);

    ln_kernel<bf16><<<TD, 64, 0, stream>>>(h, ln2s + l * DM, ln2b + l * DM, y);

    transpose_kernel<<<dim3(FF / 32, DM / 32), tb, 0, stream>>>(w1_l, wt, DM, FF);
    gemm_kernel<1><<<g3072, 256, 0, stream>>>(y, wt, b1 + l * FF, nullptr, mid, nullptr, TD, FF, DM);
    transpose_kernel<<<dim3(DM / 32, FF / 32), tb, 0, stream>>>(w2_l, wt, FF, DM);
    gemm64_kernel<2><<<g64, 256, 0, stream>>>(mid, wt, b2 + l * DM, h, nullptr, h, TD, DM, FF);
  }
  ln_kernel<float><<<TD, 64, 0, stream>>>(h, lnfs, lnfb, (float*)d_out);
}